// Round 1
// baseline (585.966 us; speedup 1.0000x reference)
//
#include <hip/hip_runtime.h>
#include <math.h>

// Problem constants (match reference)
constexpr int   B      = 2048;
constexpr int   P      = 4;
constexpr int   D      = 256;      // 64 float4 per row
constexpr int   NNEG   = 32768;
constexpr int   NTILES = NNEG / 64;   // 512 negative tiles in the GEMM
constexpr float TEMP   = 0.05f;
constexpr float ALPHA  = 0.1f;
constexpr float EPS    = 1e-12f;

// ---------------------------------------------------------------------------
// Kernel 1: per-row inverse L2 norm.  One wave (64 lanes) per row; each lane
// loads one float4 (64*4 = 256 = D), shuffle-reduce sum of squares.
// ---------------------------------------------------------------------------
__global__ void rownorm_kernel(const float* __restrict__ x,
                               float* __restrict__ inv, int nrows) {
  int w    = (blockIdx.x * blockDim.x + threadIdx.x) >> 6;
  int lane = threadIdx.x & 63;
  if (w >= nrows) return;
  float4 v = ((const float4*)(x + (size_t)w * D))[lane];
  float ss = v.x * v.x + v.y * v.y + v.z * v.z + v.w * v.w;
#pragma unroll
  for (int off = 32; off > 0; off >>= 1) ss += __shfl_xor(ss, off, 64);
  if (lane == 0) inv[w] = 1.0f / fmaxf(sqrtf(ss), EPS);
}

// ---------------------------------------------------------------------------
// Kernel 2: pos_sim[b][j] = dot(a_b, p_{b*P+j}) * inva[b] * invp[b*P+j] / T
// One wave per (b,j) pair.
// ---------------------------------------------------------------------------
__global__ void possim_kernel(const float* __restrict__ a,
                              const float* __restrict__ p,
                              const float* __restrict__ inva,
                              const float* __restrict__ invp,
                              float* __restrict__ pos_sim) {
  int w    = (blockIdx.x * blockDim.x + threadIdx.x) >> 6;  // 0..B*P-1
  int lane = threadIdx.x & 63;
  if (w >= B * P) return;
  int b = w >> 2;  // P == 4
  float4 av = ((const float4*)(a + (size_t)b * D))[lane];
  float4 pv = ((const float4*)(p + (size_t)w * D))[lane];
  float d = av.x * pv.x + av.y * pv.y + av.z * pv.z + av.w * pv.w;
#pragma unroll
  for (int off = 32; off > 0; off >>= 1) d += __shfl_xor(d, off, 64);
  if (lane == 0) pos_sim[w] = d * inva[b] * invp[w] * (1.0f / TEMP);
}

// ---------------------------------------------------------------------------
// Kernel 3: fused neg_sim GEMM + per-tile online-LSE partials.
// 64x64 output tile per block, 256 threads, 4x4 microtile per thread.
// Epilogue scales by inva*invn/T and reduces each anchor row of the tile to
// an (m, s) logsumexp partial, written to part_m/part_s[b][n_tile].
// LDS: tiles padded to 68 floats/row so &As[kk][4*t] is 16B-aligned
// (float4 ds_read_b128) and strides avoid >2-way bank conflicts.
// ---------------------------------------------------------------------------
__global__ __launch_bounds__(256) void negsim_kernel(
    const float* __restrict__ A,    // [B, D] raw anchors
    const float* __restrict__ Nn,   // [NNEG, D] raw negatives
    const float* __restrict__ inva,
    const float* __restrict__ invn,
    float* __restrict__ part_m,     // [B, NTILES]
    float* __restrict__ part_s) {   // [B, NTILES]
  __shared__ __align__(16) float As[16][68];
  __shared__ __align__(16) float Bs[16][68];
  __shared__ float red_m[64][17];
  __shared__ float red_s[64][17];

  const int tid = threadIdx.x;
  const int tx  = tid & 15;   // column group (4 cols each)
  const int ty  = tid >> 4;   // row group    (4 rows each)
  const int m0  = blockIdx.y * 64;
  const int n0  = blockIdx.x * 64;

  const int lk = tid & 15;    // k index for cooperative loads
  const int lr = tid >> 4;    // row base (4 rows, stride 16)

  float acc[4][4] = {};

  for (int k0 = 0; k0 < D; k0 += 16) {
#pragma unroll
    for (int r = 0; r < 4; r++) {
      As[lk][lr + 16 * r] = A[(size_t)(m0 + lr + 16 * r) * D + k0 + lk];
      Bs[lk][lr + 16 * r] = Nn[(size_t)(n0 + lr + 16 * r) * D + k0 + lk];
    }
    __syncthreads();
#pragma unroll
    for (int kk = 0; kk < 16; kk++) {
      float4 av = *(const float4*)&As[kk][ty * 4];
      float4 bv = *(const float4*)&Bs[kk][tx * 4];
      float a4[4] = {av.x, av.y, av.z, av.w};
      float b4[4] = {bv.x, bv.y, bv.z, bv.w};
#pragma unroll
      for (int i = 0; i < 4; i++)
#pragma unroll
        for (int j = 0; j < 4; j++)
          acc[i][j] = fmaf(a4[i], b4[j], acc[i][j]);
    }
    __syncthreads();
  }

  // Epilogue: scale and per-row online LSE within the thread's 4x4 patch.
  float ia[4], in_[4];
#pragma unroll
  for (int i = 0; i < 4; i++) ia[i] = inva[m0 + ty * 4 + i] * (1.0f / TEMP);
#pragma unroll
  for (int j = 0; j < 4; j++) in_[j] = invn[n0 + tx * 4 + j];

#pragma unroll
  for (int i = 0; i < 4; i++) {
    float s0 = acc[i][0] * ia[i] * in_[0];
    float s1 = acc[i][1] * ia[i] * in_[1];
    float s2 = acc[i][2] * ia[i] * in_[2];
    float s3 = acc[i][3] * ia[i] * in_[3];
    float mloc = fmaxf(fmaxf(s0, s1), fmaxf(s2, s3));
    float sloc = __expf(s0 - mloc) + __expf(s1 - mloc) +
                 __expf(s2 - mloc) + __expf(s3 - mloc);
    red_m[ty * 4 + i][tx] = mloc;
    red_s[ty * 4 + i][tx] = sloc;
  }
  __syncthreads();

  if (tid < 64) {
    float M = -INFINITY;
#pragma unroll
    for (int t = 0; t < 16; t++) M = fmaxf(M, red_m[tid][t]);
    float S = 0.0f;
#pragma unroll
    for (int t = 0; t < 16; t++) S += red_s[tid][t] * __expf(red_m[tid][t] - M);
    size_t idx = (size_t)(m0 + tid) * NTILES + blockIdx.x;
    part_m[idx] = M;
    part_s[idx] = S;
  }
}

// ---------------------------------------------------------------------------
// Kernel 4: combine NTILES (m,s) partials per anchor -> neg_lse[b].
// One block (256 threads) per anchor.
// ---------------------------------------------------------------------------
__global__ void lse_combine_kernel(const float* __restrict__ part_m,
                                   const float* __restrict__ part_s,
                                   float* __restrict__ neg_lse) {
  const int b = blockIdx.x;
  const int tid = threadIdx.x;
  const float* pm = part_m + (size_t)b * NTILES;
  const float* ps = part_s + (size_t)b * NTILES;

  float m = -INFINITY, s = 0.0f;
  for (int i = tid; i < NTILES; i += 256) {
    float m2 = pm[i], s2 = ps[i];
    float nm = fmaxf(m, m2);
    s = s * __expf(m - nm) + s2 * __expf(m2 - nm);  // exp(-inf)=0 on first iter
    m = nm;
  }
#pragma unroll
  for (int off = 32; off > 0; off >>= 1) {
    float m2 = __shfl_xor(m, off, 64);
    float s2 = __shfl_xor(s, off, 64);
    float nm = fmaxf(m, m2);
    s = s * __expf(m - nm) + s2 * __expf(m2 - nm);
    m = nm;
  }
  __shared__ float sm[4], ss[4];
  int wid = tid >> 6, lane = tid & 63;
  if (lane == 0) { sm[wid] = m; ss[wid] = s; }
  __syncthreads();
  if (tid == 0) {
    float M = sm[0], S = ss[0];
    for (int w = 1; w < 4; w++) {
      float nm = fmaxf(M, sm[w]);
      S = S * __expf(M - nm) + ss[w] * __expf(sm[w] - nm);
      M = nm;
    }
    neg_lse[b] = M + logf(S);
  }
}

// ---------------------------------------------------------------------------
// Kernel 5: finalize.  Single block; per-anchor pair losses + weighted-pos
// term, block-reduce, write out[0] = total / B (plain store, no atomics).
// ---------------------------------------------------------------------------
__global__ void finalize_kernel(const float* __restrict__ pos_sim,
                                const float* __restrict__ neg_lse,
                                const int* __restrict__ counts,
                                float* __restrict__ out) {
  const int tid = threadIdx.x;
  float acc = 0.0f;
  for (int b = tid; b < B; b += 256) {
    float L = neg_lse[b];
    int cnt = counts[b];
    float ps[P];
#pragma unroll
    for (int j = 0; j < P; j++) ps[j] = pos_sim[b * P + j];

    // pair losses: logaddexp(ps_j, L) - ps_j for j < cnt
#pragma unroll
    for (int j = 0; j < P; j++) {
      if (j < cnt) {
        float hi = fmaxf(ps[j], L), lo = fminf(ps[j], L);
        float la = hi + log1pf(__expf(lo - hi));
        acc += la - ps[j];
      }
    }
    // softmax over all P columns (reference does NOT mask here)
    float mp = fmaxf(fmaxf(ps[0], ps[1]), fmaxf(ps[2], ps[3]));
    float e0 = __expf(ps[0] - mp), e1 = __expf(ps[1] - mp);
    float e2 = __expf(ps[2] - mp), e3 = __expf(ps[3] - mp);
    float se = e0 + e1 + e2 + e3;
    float wps = (e0 * ps[0] + e1 * ps[1] + e2 * ps[2] + e3 * ps[3]) / se;
    if (cnt > 1) {
      float hi = fmaxf(wps, L), lo = fminf(wps, L);
      float wl = hi + log1pf(__expf(lo - hi)) - wps;
      acc += ALPHA * wl;
    }
  }
  // block reduce (4 waves)
#pragma unroll
  for (int off = 32; off > 0; off >>= 1) acc += __shfl_xor(acc, off, 64);
  __shared__ float sa[4];
  int wid = tid >> 6, lane = tid & 63;
  if (lane == 0) sa[wid] = acc;
  __syncthreads();
  if (tid == 0) out[0] = (sa[0] + sa[1] + sa[2] + sa[3]) / (float)B;
}

// ---------------------------------------------------------------------------
extern "C" void kernel_launch(void* const* d_in, const int* in_sizes, int n_in,
                              void* d_out, int out_size, void* d_ws,
                              size_t ws_size, hipStream_t stream) {
  const float* anc    = (const float*)d_in[0];
  const float* pos    = (const float*)d_in[1];
  const float* neg    = (const float*)d_in[2];
  const int*   counts = (const int*)d_in[3];
  float* out = (float*)d_out;

  // Workspace layout (floats): ~8.6 MB total
  float* ws      = (float*)d_ws;
  float* inv_a   = ws;                        // B
  float* inv_p   = inv_a + B;                 // B*P
  float* inv_n   = inv_p + B * P;             // NNEG
  float* pos_sim = inv_n + NNEG;              // B*P
  float* neg_lse = pos_sim + B * P;           // B
  float* part_m  = neg_lse + B;               // B*NTILES
  float* part_s  = part_m + (size_t)B * NTILES;

  rownorm_kernel<<<B / 4, 256, 0, stream>>>(anc, inv_a, B);
  rownorm_kernel<<<B * P / 4, 256, 0, stream>>>(pos, inv_p, B * P);
  rownorm_kernel<<<NNEG / 4, 256, 0, stream>>>(neg, inv_n, NNEG);
  possim_kernel<<<B * P / 4, 256, 0, stream>>>(anc, pos, inv_a, inv_p, pos_sim);

  dim3 grid(NNEG / 64, B / 64);  // (512, 32)
  negsim_kernel<<<grid, 256, 0, stream>>>(anc, neg, inv_a, inv_n, part_m, part_s);

  lse_combine_kernel<<<B, 256, 0, stream>>>(part_m, part_s, neg_lse);
  finalize_kernel<<<1, 256, 0, stream>>>(pos_sim, neg_lse, counts, out);
}

// Round 2
// 190.532 us; speedup vs baseline: 3.0754x; 3.0754x over previous
//
#include <hip/hip_runtime.h>
#include <math.h>

// Problem constants (match reference)
constexpr int   B       = 2048;
constexpr int   P       = 4;
constexpr int   D       = 256;       // K of the GEMM
constexpr int   NNEG    = 32768;
constexpr int   NTILES  = NNEG / 64; // 512 per-row (m,s) partials (64-col patches)
constexpr float TEMP    = 0.05f;
constexpr float ALPHA   = 0.1f;
constexpr float EPS     = 1e-12f;
constexpr float INV_T   = 1.0f / TEMP;

typedef __bf16 bf16x8 __attribute__((ext_vector_type(8)));
typedef float  f32x4  __attribute__((ext_vector_type(4)));

// fp32 -> bf16 (RNE), bit-level, no NaN inputs here
__device__ inline unsigned short f2bf(float f) {
  unsigned int u = __float_as_uint(f);
  u = (u + 0x7fffu + ((u >> 16) & 1u)) >> 16;
  return (unsigned short)u;
}

// ---------------------------------------------------------------------------
// Kernel 1: per-row L2-normalize + cast to bf16.  One wave per row.
// ---------------------------------------------------------------------------
__global__ void norm_cast_kernel(const float* __restrict__ x,
                                 unsigned short* __restrict__ out, int nrows) {
  int w    = (blockIdx.x * blockDim.x + threadIdx.x) >> 6;
  int lane = threadIdx.x & 63;
  if (w >= nrows) return;
  float4 v = ((const float4*)(x + (size_t)w * D))[lane];
  float ss = v.x * v.x + v.y * v.y + v.z * v.z + v.w * v.w;
#pragma unroll
  for (int off = 32; off > 0; off >>= 1) ss += __shfl_xor(ss, off, 64);
  float inv = 1.0f / fmaxf(sqrtf(ss), EPS);
  ushort4 o;
  o.x = f2bf(v.x * inv); o.y = f2bf(v.y * inv);
  o.z = f2bf(v.z * inv); o.w = f2bf(v.w * inv);
  ((ushort4*)(out + (size_t)w * D))[lane] = o;
}

// ---------------------------------------------------------------------------
// Kernel 2: pos_sim[b][j] (exact fp32).  One wave per (b,j) pair; three
// simultaneous shuffle reductions (dot, |a|^2, |p|^2).
// ---------------------------------------------------------------------------
__global__ void possim_kernel(const float* __restrict__ a,
                              const float* __restrict__ p,
                              float* __restrict__ pos_sim) {
  int w    = (blockIdx.x * blockDim.x + threadIdx.x) >> 6;  // 0..B*P-1
  int lane = threadIdx.x & 63;
  if (w >= B * P) return;
  int b = w >> 2;  // P == 4
  float4 av = ((const float4*)(a + (size_t)b * D))[lane];
  float4 pv = ((const float4*)(p + (size_t)w * D))[lane];
  float d  = av.x * pv.x + av.y * pv.y + av.z * pv.z + av.w * pv.w;
  float sa = av.x * av.x + av.y * av.y + av.z * av.z + av.w * av.w;
  float sp = pv.x * pv.x + pv.y * pv.y + pv.z * pv.z + pv.w * pv.w;
#pragma unroll
  for (int off = 32; off > 0; off >>= 1) {
    d  += __shfl_xor(d, off, 64);
    sa += __shfl_xor(sa, off, 64);
    sp += __shfl_xor(sp, off, 64);
  }
  if (lane == 0) {
    float inva = 1.0f / fmaxf(sqrtf(sa), EPS);
    float invp = 1.0f / fmaxf(sqrtf(sp), EPS);
    pos_sim[w] = d * inva * invp * INV_T;
  }
}

// ---------------------------------------------------------------------------
// Kernel 3: bf16 MFMA GEMM (C = A_bf . N_bf^T) fused with per-row online-LSE
// partials.  m97 structure: 128x128 tile, 256 threads = 4 waves (2x2), each
// wave a 64x64 microtile = 4x4 x mfma_f32_16x16x32_bf16.  BK=64, K=256 -> 4
// iterations, global->LDS staging via global_load_lds width=16 (LDS layout is
// exactly lane-order contiguous: lane l -> byte offset l*16, NO padding).
// Epilogue: scale by 1/T, per-row (m, s) over the wave's 64 cols via 16-lane
// shuffle reduce, write part_m/part_s[row][colpatch].
// ---------------------------------------------------------------------------
constexpr int BM = 128, BN = 128, BK = 64;

__global__ __launch_bounds__(256) void negsim_mfma_kernel(
    const unsigned short* __restrict__ Abf,  // [B][D] normalized bf16
    const unsigned short* __restrict__ Nbf,  // [NNEG][D] normalized bf16
    float* __restrict__ part_m,              // [B][NTILES]
    float* __restrict__ part_s) {            // [B][NTILES]
  __shared__ unsigned short As[BM * BK];  // 16 KB, row-major [row][k]
  __shared__ unsigned short Bs[BN * BK];  // 16 KB

  const int tid  = threadIdx.x;
  const int wave = tid >> 6;
  const int lane = tid & 63;
  const int wx   = wave & 1;   // N direction (2 waves)
  const int wy   = wave >> 1;  // M direction (2 waves)
  const int m0   = blockIdx.y * BM;
  const int n0   = blockIdx.x * BN;

  const int lrow = lane >> 3;        // 0..7  : row within an 8-row stage group
  const int lcol = (lane & 7) * 8;   // 0..56 : k offset (8 bf16 = 16 B)

  f32x4 acc[4][4] = {};

  for (int k0 = 0; k0 < D; k0 += BK) {
#pragma unroll
    for (int i = 0; i < 4; i++) {
      const int r0 = (wave * 4 + i) * 8;  // 8-row group; waves cover 0..127
      // A tile
      __builtin_amdgcn_global_load_lds(
          (const __attribute__((address_space(1))) unsigned int*)
              (Abf + (size_t)(m0 + r0 + lrow) * D + k0 + lcol),
          (__attribute__((address_space(3))) unsigned int*)(As + r0 * BK),
          16, 0, 0);
      // B tile
      __builtin_amdgcn_global_load_lds(
          (const __attribute__((address_space(1))) unsigned int*)
              (Nbf + (size_t)(n0 + r0 + lrow) * D + k0 + lcol),
          (__attribute__((address_space(3))) unsigned int*)(Bs + r0 * BK),
          16, 0, 0);
    }
    __syncthreads();  // drains vmcnt(0) for global_load_lds, then barrier

#pragma unroll
    for (int kk = 0; kk < BK; kk += 32) {
      const int ko = kk + (lane >> 4) * 8;  // this lane's k offset in frag
      bf16x8 af[4], bfr[4];
#pragma unroll
      for (int mi = 0; mi < 4; mi++)
        af[mi] = *(const bf16x8*)&As[(wy * 64 + mi * 16 + (lane & 15)) * BK + ko];
#pragma unroll
      for (int ni = 0; ni < 4; ni++)
        bfr[ni] = *(const bf16x8*)&Bs[(wx * 64 + ni * 16 + (lane & 15)) * BK + ko];
#pragma unroll
      for (int mi = 0; mi < 4; mi++)
#pragma unroll
        for (int ni = 0; ni < 4; ni++)
          acc[mi][ni] = __builtin_amdgcn_mfma_f32_16x16x32_bf16(
              af[mi], bfr[ni], acc[mi][ni], 0, 0, 0);
    }
    __syncthreads();  // all reads done before next stage overwrites
  }

  // Epilogue: C/D layout (16x16x32): row = mi*16 + (lane>>4)*4 + r,
  // col = ni*16 + (lane&15).  Per (mi,r): 4 values/lane (ni), the row spans
  // the 16 lanes sharing lane>>4.
#pragma unroll
  for (int mi = 0; mi < 4; mi++) {
#pragma unroll
    for (int r = 0; r < 4; r++) {
      float v0 = acc[mi][0][r] * INV_T;
      float v1 = acc[mi][1][r] * INV_T;
      float v2 = acc[mi][2][r] * INV_T;
      float v3 = acc[mi][3][r] * INV_T;
      float m = fmaxf(fmaxf(v0, v1), fmaxf(v2, v3));
      float s = __expf(v0 - m) + __expf(v1 - m) + __expf(v2 - m) + __expf(v3 - m);
#pragma unroll
      for (int off = 1; off < 16; off <<= 1) {  // reduce across low-4 lane bits
        float m2 = __shfl_xor(m, off, 64);
        float s2 = __shfl_xor(s, off, 64);
        float nm = fmaxf(m, m2);
        s = s * __expf(m - nm) + s2 * __expf(m2 - nm);
        m = nm;
      }
      if ((lane & 15) == 0) {
        int row = m0 + wy * 64 + mi * 16 + (lane >> 4) * 4 + r;
        int cp  = blockIdx.x * 2 + wx;  // 64-col patch index
        part_m[(size_t)row * NTILES + cp] = m;
        part_s[(size_t)row * NTILES + cp] = s;
      }
    }
  }
}

// ---------------------------------------------------------------------------
// Kernel 4: combine NTILES (m,s) partials per anchor -> neg_lse[b].
// ---------------------------------------------------------------------------
__global__ void lse_combine_kernel(const float* __restrict__ part_m,
                                   const float* __restrict__ part_s,
                                   float* __restrict__ neg_lse) {
  const int b = blockIdx.x;
  const int tid = threadIdx.x;
  const float* pm = part_m + (size_t)b * NTILES;
  const float* ps = part_s + (size_t)b * NTILES;

  float m = -INFINITY, s = 0.0f;
  for (int i = tid; i < NTILES; i += 256) {
    float m2 = pm[i], s2 = ps[i];
    float nm = fmaxf(m, m2);
    s = s * __expf(m - nm) + s2 * __expf(m2 - nm);
    m = nm;
  }
#pragma unroll
  for (int off = 32; off > 0; off >>= 1) {
    float m2 = __shfl_xor(m, off, 64);
    float s2 = __shfl_xor(s, off, 64);
    float nm = fmaxf(m, m2);
    s = s * __expf(m - nm) + s2 * __expf(m2 - nm);
    m = nm;
  }
  __shared__ float sm[4], ss[4];
  int wid = tid >> 6, lane = tid & 63;
  if (lane == 0) { sm[wid] = m; ss[wid] = s; }
  __syncthreads();
  if (tid == 0) {
    float M = sm[0], S = ss[0];
    for (int w = 1; w < 4; w++) {
      float nm = fmaxf(M, sm[w]);
      S = S * __expf(M - nm) + ss[w] * __expf(sm[w] - nm);
      M = nm;
    }
    neg_lse[b] = M + logf(S);
  }
}

// ---------------------------------------------------------------------------
// Kernel 5: finalize.  Single block; pair losses + weighted-pos term,
// block-reduce, out[0] = total / B (plain store, survives d_out poisoning).
// ---------------------------------------------------------------------------
__global__ void finalize_kernel(const float* __restrict__ pos_sim,
                                const float* __restrict__ neg_lse,
                                const int* __restrict__ counts,
                                float* __restrict__ out) {
  const int tid = threadIdx.x;
  float acc = 0.0f;
  for (int b = tid; b < B; b += 256) {
    float L = neg_lse[b];
    int cnt = counts[b];
    float ps[P];
#pragma unroll
    for (int j = 0; j < P; j++) ps[j] = pos_sim[b * P + j];

#pragma unroll
    for (int j = 0; j < P; j++) {
      if (j < cnt) {
        float hi = fmaxf(ps[j], L), lo = fminf(ps[j], L);
        acc += hi + log1pf(__expf(lo - hi)) - ps[j];
      }
    }
    float mp = fmaxf(fmaxf(ps[0], ps[1]), fmaxf(ps[2], ps[3]));
    float e0 = __expf(ps[0] - mp), e1 = __expf(ps[1] - mp);
    float e2 = __expf(ps[2] - mp), e3 = __expf(ps[3] - mp);
    float se = e0 + e1 + e2 + e3;
    float wps = (e0 * ps[0] + e1 * ps[1] + e2 * ps[2] + e3 * ps[3]) / se;
    if (cnt > 1) {
      float hi = fmaxf(wps, L), lo = fminf(wps, L);
      acc += ALPHA * (hi + log1pf(__expf(lo - hi)) - wps);
    }
  }
#pragma unroll
  for (int off = 32; off > 0; off >>= 1) acc += __shfl_xor(acc, off, 64);
  __shared__ float sa[4];
  int wid = tid >> 6, lane = tid & 63;
  if (lane == 0) sa[wid] = acc;
  __syncthreads();
  if (tid == 0) out[0] = (sa[0] + sa[1] + sa[2] + sa[3]) / (float)B;
}

// ---------------------------------------------------------------------------
extern "C" void kernel_launch(void* const* d_in, const int* in_sizes, int n_in,
                              void* d_out, int out_size, void* d_ws,
                              size_t ws_size, hipStream_t stream) {
  const float* anc    = (const float*)d_in[0];
  const float* pos    = (const float*)d_in[1];
  const float* neg    = (const float*)d_in[2];
  const int*   counts = (const int*)d_in[3];
  float* out = (float*)d_out;

  // Workspace layout: ~25.1 MB
  unsigned short* a_bf = (unsigned short*)d_ws;          // B*D      (1 MB)
  unsigned short* n_bf = a_bf + (size_t)B * D;           // NNEG*D   (16 MB)
  float* part_m  = (float*)(n_bf + (size_t)NNEG * D);    // B*NTILES (4 MB)
  float* part_s  = part_m + (size_t)B * NTILES;          // B*NTILES (4 MB)
  float* pos_sim = part_s + (size_t)B * NTILES;          // B*P
  float* neg_lse = pos_sim + B * P;                      // B

  norm_cast_kernel<<<B / 4, 256, 0, stream>>>(anc, a_bf, B);
  norm_cast_kernel<<<NNEG / 4, 256, 0, stream>>>(neg, n_bf, NNEG);
  possim_kernel<<<B * P / 4, 256, 0, stream>>>(anc, pos, pos_sim);

  dim3 grid(NNEG / BN, B / BM);  // (256, 16) = 4096 blocks
  negsim_mfma_kernel<<<grid, 256, 0, stream>>>(a_bf, n_bf, part_m, part_s);

  lse_combine_kernel<<<B, 256, 0, stream>>>(part_m, part_s, neg_lse);
  finalize_kernel<<<1, 256, 0, stream>>>(pos_sim, neg_lse, counts, out);
}